// Round 6
// baseline (515.236 us; speedup 1.0000x reference)
//
#include <hip/hip_runtime.h>
#include <hip/hip_bf16.h>
#include <cstdint>
#include <cstddef>

typedef __attribute__((ext_vector_type(8))) short short8;
typedef __attribute__((ext_vector_type(4))) float f32x4;

#define AS1U32(p) ((const __attribute__((address_space(1))) uint32_t*)(p))
#define AS3U32(p) ((__attribute__((address_space(3))) uint32_t*)(p))

__device__ __forceinline__ unsigned short f2bf(float v) {
  union { float f; uint32_t u; } a; a.f = v;
  uint32_t u = a.u;
  u += 0x7FFFu + ((u >> 16) & 1u);   // round-to-nearest-even
  return (unsigned short)(u >> 16);
}

// gelu(x) = x * sigmoid(2u), u = sqrt(2/pi)(x + 0.044715 x^3)
// exp2-folded: sig = 1/(1+exp2(x*(A + B*x^2))), A = -2*c0*log2e, B = A*c1
__device__ __forceinline__ float gelu_fast(float x) {
  const float A = -2.302118142f;      // -2*0.7978845608*1.4426950409
  const float B = -0.102943494f;      // A*0.044715
  float x2 = x * x;
  float t = x * __builtin_fmaf(B, x2, A);
  float e = __builtin_amdgcn_exp2f(t);
  return x * __builtin_amdgcn_rcpf(1.0f + e);
}

// ---------------- prologue kernels ----------------

// partial token-sums: kpart[b*512+d] = sum_{i<128} x[(b*128+i)*512+d]
// 128 blocks: balances parallel-phase BW vs gate_all's single-block re-read.
__global__ __launch_bounds__(512)
void reduce_part(const float* __restrict__ x, float* __restrict__ kpart) {
  const int d = threadIdx.x;
  const int b = blockIdx.x;
  float s = 0.f;
#pragma unroll 4
  for (int i = 0; i < 128; i++)
    s += x[((size_t)b * 128 + i) * 512 + d];
  kpart[(size_t)b * 512 + d] = s;
}

__global__ __launch_bounds__(1024)
void gate_all(const float* __restrict__ kpart,
              const float* __restrict__ gate_w,
              const float* __restrict__ gate_b,
              const float* __restrict__ b1, const float* __restrict__ b2,
              int* __restrict__ idxout,
              float* __restrict__ b1cat, float* __restrict__ b2sel) {
  __shared__ float ksum2[2][512];
  __shared__ float coarse[16];
  __shared__ int idxl[4];
  const int t = threadIdx.x;
  {
    const int d = t & 511, h = t >> 9;
    float s = 0.f;
    for (int p = h * 64; p < h * 64 + 64; p++) s += kpart[(size_t)p * 512 + d];
    ksum2[h][d] = s;
  }
  __syncthreads();
  {
    const int wave = t >> 6, lane = t & 63;
    const int d0 = lane * 8;
    float s = 0.f;
#pragma unroll
    for (int j = 0; j < 8; j++)
      s += gate_w[wave * 512 + d0 + j] * (ksum2[0][d0 + j] + ksum2[1][d0 + j]);
#pragma unroll
    for (int off = 32; off >= 1; off >>= 1) s += __shfl_down(s, off, 64);
    if (lane == 0) coarse[wave] = s + gate_b[wave];
  }
  __syncthreads();
  if (t == 0) {
    unsigned taken = 0;
    for (int r = 0; r < 4; r++) {
      float best = -3.4e38f; int bi = 0;
      for (int e = 0; e < 16; e++)
        if (!((taken >> e) & 1u) && coarse[e] > best) { best = coarse[e]; bi = e; }
      taken |= 1u << bi;
      idxl[r] = bi; idxout[r] = bi;
    }
  }
  __syncthreads();
  for (int i = t; i < 8192; i += 1024)
    b1cat[i] = b1[(size_t)idxl[i >> 11] * 2048 + (i & 2047)];
  for (int i = t; i < 2048; i += 1024)
    b2sel[i] = b2[(size_t)idxl[i >> 9] * 512 + (i & 511)];
}

// prep_fused: one launch for (a) per-token softmax gate + x->bf16 (blocks
// [0,4096)) and (b) W1/W2 transpose+bf16-convert (blocks [4096,6144)).
// Both depend only on idx. Transpose is vectorized: float4 loads (16 B/lane),
// ushort4 stores (8 B/lane) — the old kernel's 4B/2B scalar accesses were a
// G13 violation. LDS bank check on tl[64][65]: read addr%32 = (4*tx4g+j+ty),
// 64 lanes -> every bank exactly 2-way = free.
__global__ __launch_bounds__(256)
void prep_fused(const float* __restrict__ x,
                const float* __restrict__ gate_w,
                const float* __restrict__ gate_b,
                const int* __restrict__ idx,
                float* __restrict__ gwout,
                unsigned short* __restrict__ xbf,
                const float* __restrict__ w1, const float* __restrict__ w2,
                unsigned short* __restrict__ w1t, unsigned short* __restrict__ w2t) {
  __shared__ float smem[64 * 65];      // transpose tile; softmax aliases first 2052
  const int tid = threadIdx.x;
  const int bid = blockIdx.x;

  if (bid < 4096) {
    // ---- softmax gate + xconv ----
    float* wsel = smem;                // [4][512]
    float* bsel = smem + 2048;         // [4]
    for (int i = tid; i < 2048; i += 256) {
      int k = i >> 9;
      wsel[(size_t)k * 512 + (i & 511)] = gate_w[(size_t)idx[k] * 512 + (i & 511)];
    }
    if (tid < 4) bsel[tid] = gate_b[idx[tid]];
    __syncthreads();
    const int wave = tid >> 6, lane = tid & 63;
    const int t = bid * 4 + wave;
    const float* xr = x + (size_t)t * 512 + lane * 8;
    float4 v0 = ((const float4*)xr)[0];
    float4 v1 = ((const float4*)xr)[1];
    float vals[8] = {v0.x, v0.y, v0.z, v0.w, v1.x, v1.y, v1.z, v1.w};
    short8 pk;
#pragma unroll
    for (int j = 0; j < 8; j++) pk[j] = (short)f2bf(vals[j]);
    *(short8*)(xbf + (size_t)t * 512 + lane * 8) = pk;
    float a0 = 0.f, a1 = 0.f, a2 = 0.f, a3 = 0.f;
    const int dbase = lane * 8;
#pragma unroll
    for (int j = 0; j < 8; j++) {
      float xv = vals[j];
      a0 += xv * wsel[dbase + j];
      a1 += xv * wsel[512 + dbase + j];
      a2 += xv * wsel[1024 + dbase + j];
      a3 += xv * wsel[1536 + dbase + j];
    }
#pragma unroll
    for (int off = 32; off >= 1; off >>= 1) {
      a0 += __shfl_down(a0, off, 64);
      a1 += __shfl_down(a1, off, 64);
      a2 += __shfl_down(a2, off, 64);
      a3 += __shfl_down(a3, off, 64);
    }
    if (lane == 0) {
      float l0 = a0 + bsel[0], l1 = a1 + bsel[1], l2 = a2 + bsel[2], l3 = a3 + bsel[3];
      float m = fmaxf(fmaxf(l0, l1), fmaxf(l2, l3));
      float e0 = __expf(l0 - m), e1 = __expf(l1 - m);
      float e2 = __expf(l2 - m), e3 = __expf(l3 - m);
      float inv = 1.0f / (e0 + e1 + e2 + e3);
      float* o = gwout + (size_t)t * 4;
      o[0] = e0 * inv; o[1] = e1 * inv; o[2] = e2 * inv; o[3] = e3 * inv;
    }
  } else {
    // ---- transpose + bf16 convert (64x64 tile per block) ----
    const int zz = bid - 4096;
    const int z = zz >> 8;
    const int rem = zz & 255;
    const int bx = rem & 7, by = rem >> 3;
    const float* src; unsigned short* dbase; int C, dstLd, r0, c0;
    if (z < 4) {
      src = w1 + (size_t)idx[z] * 512 * 2048;
      dbase = w1t + (size_t)z * 2048 * 512;
      C = 2048; dstLd = 512;
      r0 = bx * 64; c0 = by * 64;        // r in [0,512), c in [0,2048)
    } else {
      src = w2 + (size_t)idx[z - 4] * 2048 * 512;
      dbase = w2t + (size_t)(z - 4) * 2048;
      C = 512; dstLd = 8192;
      r0 = by * 64; c0 = bx * 64;        // r in [0,2048), c in [0,512)
    }
    float (*tl)[65] = (float(*)[65])smem;
    const int tx4 = (tid & 15) * 4;      // col group of 4
    const int ty = tid >> 4;             // 16 rows per pass
#pragma unroll
    for (int i = 0; i < 4; i++) {
      int r = i * 16 + ty;
      float4 v = *(const float4*)&src[(size_t)(r0 + r) * C + c0 + tx4];
      tl[r][tx4 + 0] = v.x; tl[r][tx4 + 1] = v.y;
      tl[r][tx4 + 2] = v.z; tl[r][tx4 + 3] = v.w;
    }
    __syncthreads();
#pragma unroll
    for (int i = 0; i < 4; i++) {
      int rr = i * 16 + ty;
      ushort4 o;
      o.x = f2bf(tl[tx4 + 0][rr]);
      o.y = f2bf(tl[tx4 + 1][rr]);
      o.z = f2bf(tl[tx4 + 2][rr]);
      o.w = f2bf(tl[tx4 + 3][rr]);
      *(ushort4*)&dbase[(size_t)(c0 + rr) * dstLd + r0 + tx4] = o;
    }
  }
}

// ---------------- gemm_bt: 128x128 2-barrier kernel (gemm1) ----------------
// K=512 short-K, gelu epilogue: 32 KiB LDS -> 3 blocks/CU (measured 37% occ);
// cross-block overlap hides barrier drains + epilogue. Proven 91 us.
// (Round-5 A/B: the 4-phase dbuf version at 64 KiB LDS = 2 blocks/CU ran
// 100.5 us — short-K wants occupancy, not pipeline depth.)
template <int EPI>
__global__ __launch_bounds__(256, 2)
void gemm_bt(const unsigned short* __restrict__ A,
             const unsigned short* __restrict__ Bt,
             void* __restrict__ C, int K, int lda, int ldb, int ldc,
             const float* __restrict__ gw,
             const float* __restrict__ bias, int colOff, int accum) {
  __shared__ unsigned short lA[128 * 64];
  __shared__ unsigned short lB[128 * 64];
  const int tid = threadIdx.x;
  const int wave = tid >> 6;
  const int lane = tid & 63;
  const int rowA0 = blockIdx.x * 128;
  const int rowB0 = blockIdx.y * 128;

  f32x4 acc[4][4];
#pragma unroll
  for (int i = 0; i < 4; i++)
#pragma unroll
    for (int j = 0; j < 4; j++) acc[i][j] = (f32x4){0.f, 0.f, 0.f, 0.f};

  const int lrow = lane >> 3;
  const int lslot = lane & 7;
  const int gchunk = lslot ^ lrow;
  const int fr = lane & 15;
  const int quad = lane >> 4;
  const int wm = (wave >> 1) * 64;
  const int wn = (wave & 1) * 64;
  const int swz = fr & 7;

  for (int kt = 0; kt < K; kt += 64) {
#pragma unroll
    for (int c = 0; c < 4; c++) {
      int r = wave * 32 + c * 8 + lrow;
      const unsigned short* gp = A + (size_t)(rowA0 + r) * lda + kt + gchunk * 8;
      __builtin_amdgcn_global_load_lds(AS1U32(gp), AS3U32(lA + (wave * 32 + c * 8) * 64), 16, 0, 0);
    }
#pragma unroll
    for (int c = 0; c < 4; c++) {
      int r = wave * 32 + c * 8 + lrow;
      const unsigned short* gp = Bt + (size_t)(rowB0 + r) * ldb + kt + gchunk * 8;
      __builtin_amdgcn_global_load_lds(AS1U32(gp), AS3U32(lB + (wave * 32 + c * 8) * 64), 16, 0, 0);
    }
    __syncthreads();
#pragma unroll
    for (int ks = 0; ks < 2; ks++) {
      short8 af[4], bfr[4];
      const int c = ks * 4 + quad;
      const int slot = (c ^ swz) << 3;
#pragma unroll
      for (int i = 0; i < 4; i++)
        af[i] = *(const short8*)(lA + (wm + i * 16 + fr) * 64 + slot);
#pragma unroll
      for (int j = 0; j < 4; j++)
        bfr[j] = *(const short8*)(lB + (wn + j * 16 + fr) * 64 + slot);
#pragma unroll
      for (int i = 0; i < 4; i++)
#pragma unroll
        for (int j = 0; j < 4; j++)
          acc[i][j] = __builtin_amdgcn_mfma_f32_16x16x32_bf16(af[i], bfr[j], acc[i][j], 0, 0, 0);
    }
    __syncthreads();
  }

  if (EPI == 1) {
    unsigned short* Cb = (unsigned short*)C;
    const int kexp = (colOff + rowB0) >> 11;
#pragma unroll
    for (int i = 0; i < 4; i++) {
#pragma unroll
      for (int reg = 0; reg < 4; reg++) {
        int r = rowA0 + wm + i * 16 + quad * 4 + reg;
        float g = gw[(size_t)r * 4 + kexp];
#pragma unroll
        for (int j = 0; j < 4; j++) {
          int n = rowB0 + wn + j * 16 + fr;
          float v = acc[i][j][reg] + bias[colOff + n];
          Cb[(size_t)r * ldc + n] = f2bf(gelu_fast(v) * g);
        }
      }
    }
  } else {
    float* Cf = (float*)C;
#pragma unroll
    for (int i = 0; i < 4; i++) {
#pragma unroll
      for (int reg = 0; reg < 4; reg++) {
        int r = rowA0 + wm + i * 16 + quad * 4 + reg;
        size_t t4 = (size_t)r * 4;
        float g0 = gw[t4], g1 = gw[t4 + 1], g2 = gw[t4 + 2], g3 = gw[t4 + 3];
#pragma unroll
        for (int j = 0; j < 4; j++) {
          int n = rowB0 + wn + j * 16 + fr;
          size_t ci = (size_t)r * 512 + n;
          float v = acc[i][j][reg];
          if (accum) v += Cf[ci];
          else v += g0 * bias[n] + g1 * bias[512 + n] +
                    g2 * bias[1024 + n] + g3 * bias[1536 + n];
          Cf[ci] = v;
        }
      }
    }
  }
}

// ---------------- gemm4p: 4-phase double-buffered 128x128 tile (gemm2) ----------------
// Long-K (slabDF) only. 64 KiB LDS -> 2 blocks/CU; counted-vmcnt pipeline +
// cross-block overlap. Measured ~61 us/slab (round-5 delta arithmetic).
//   P0: ds_read ALL buf0 frags | BAR | lgkm0 | MFMA ks=0 | BAR
//   P1: stage next buf0 tile (8 loads) | MFMA ks=1 | vmcnt(8) | BAR
//   P2/P3: same for buf1. VMW(8) = oldest in-flight tile landed.
// No XCD swizzle: natural lin id stride for A-sharing blocks is gridDim.x
// = 0 mod 8 -> they share one XCD L2 (round-2 lesson).

#define CFENCE asm volatile("" ::: "memory")
#define BAR    do { CFENCE; __builtin_amdgcn_s_barrier(); CFENCE; } while (0)
#define LGKM0  do { asm volatile("s_waitcnt lgkmcnt(0)" ::: "memory"); \
                    __builtin_amdgcn_sched_barrier(0); } while (0)
#define SCHEDB __builtin_amdgcn_sched_barrier(0)
#define VMW(n) asm volatile("s_waitcnt vmcnt(" #n ")" ::: "memory")

#define LDALL(abuf, bbuf)                                                   \
  do {                                                                      \
    _Pragma("unroll")                                                       \
    for (int i_ = 0; i_ < 4; i_++)                                          \
      _Pragma("unroll")                                                     \
      for (int ks_ = 0; ks_ < 2; ks_++)                                     \
        aF[i_][ks_] = *(const short8*)((abuf) +                             \
            (size_t)(wm + i_ * 16 + fr) * 64 +                              \
            (((ks_ * 4 + quad) ^ swz) << 3));                               \
    _Pragma("unroll")                                                       \
    for (int j_ = 0; j_ < 4; j_++)                                          \
      _Pragma("unroll")                                                     \
      for (int ks_ = 0; ks_ < 2; ks_++)                                     \
        bF[j_][ks_] = *(const short8*)((bbuf) +                             \
            (size_t)(wn + j_ * 16 + fr) * 64 +                              \
            (((ks_ * 4 + quad) ^ swz) << 3));                               \
  } while (0)

#define MMH(ks)                                                             \
  do {                                                                      \
    __builtin_amdgcn_s_setprio(1);                                          \
    _Pragma("unroll")                                                       \
    for (int i_ = 0; i_ < 4; i_++)                                          \
      _Pragma("unroll")                                                     \
      for (int j_ = 0; j_ < 4; j_++)                                        \
        acc[i_][j_] = __builtin_amdgcn_mfma_f32_16x16x32_bf16(              \
            aF[i_][ks], bF[j_][ks], acc[i_][j_], 0, 0, 0);                  \
    __builtin_amdgcn_s_setprio(0);                                          \
  } while (0)

template <int EPI>
__global__ __launch_bounds__(256, 2)
void gemm4p(const unsigned short* __restrict__ A,
            const unsigned short* __restrict__ Bt,
            void* __restrict__ C, int K, int lda, int ldb, int ldc,
            const float* __restrict__ gw,
            const float* __restrict__ bias, int colOff, int accum) {
  __shared__ unsigned short lds[4 * 128 * 64];
  const int tid = threadIdx.x;
  const int wave = tid >> 6, lane = tid & 63;
  const int lrow = lane >> 3, lslot = lane & 7, gch = lslot ^ lrow;
  const int fr = lane & 15, quad = lane >> 4, swz = fr & 7;
  const int wm = (wave >> 1) * 64, wn = (wave & 1) * 64;
  const int rowA0 = blockIdx.x * 128;
  const int rowB0 = blockIdx.y * 128;

  unsigned short* const A0 = lds;
  unsigned short* const B0 = lds + 128 * 64;
  unsigned short* const A1 = lds + 2 * 128 * 64;
  unsigned short* const B1 = lds + 3 * 128 * 64;

  auto stT = [&](unsigned short* ab, unsigned short* bb, int kt) {
#pragma unroll
    for (int c = 0; c < 4; c++) {
      int r = wave * 32 + c * 8 + lrow;
      const unsigned short* gp = A + (size_t)(rowA0 + r) * lda + kt + gch * 8;
      __builtin_amdgcn_global_load_lds(AS1U32(gp), AS3U32(ab + (wave * 32 + c * 8) * 64), 16, 0, 0);
    }
#pragma unroll
    for (int c = 0; c < 4; c++) {
      int r = wave * 32 + c * 8 + lrow;
      const unsigned short* gp = Bt + (size_t)(rowB0 + r) * ldb + kt + gch * 8;
      __builtin_amdgcn_global_load_lds(AS1U32(gp), AS3U32(bb + (wave * 32 + c * 8) * 64), 16, 0, 0);
    }
  };

  f32x4 acc[4][4];
#pragma unroll
  for (int i = 0; i < 4; i++)
#pragma unroll
    for (int j = 0; j < 4; j++) acc[i][j] = (f32x4){0.f, 0.f, 0.f, 0.f};

  short8 aF[4][2];
  short8 bF[4][2];

  // ---- prologue: tile0 -> buf0, tile1 -> buf1 ----
  stT(A0, B0, 0);
  stT(A1, B1, 64);
  VMW(8);            // oldest 8 = tile0 landed (tile1 may be in flight)
  BAR;

  const int niter = K >> 7;   // two 64-K tiles per iteration
  for (int i = 0; i < niter - 1; i++) {
    const int kt = i * 128;
    LDALL(A0, B0);
    BAR; LGKM0; MMH(0); BAR;
    stT(A0, B0, kt + 128); SCHEDB;
    MMH(1); VMW(8); BAR;
    LDALL(A1, B1);
    BAR; LGKM0; MMH(0); BAR;
    stT(A1, B1, kt + 192); SCHEDB;
    MMH(1); VMW(8); BAR;
  }
  // ---- peeled last iteration (no staging) ----
  LDALL(A0, B0);
  BAR; LGKM0; MMH(0); BAR;
  MMH(1); VMW(0); BAR;
  LDALL(A1, B1);
  BAR; LGKM0; MMH(0); BAR;
  MMH(1);

  // ---- epilogue ----
  if (EPI == 1) {
    unsigned short* Cb = (unsigned short*)C;
    const int kexp = (colOff + rowB0) >> 11;
#pragma unroll
    for (int i = 0; i < 4; i++) {
#pragma unroll
      for (int reg = 0; reg < 4; reg++) {
        int r = rowA0 + wm + i * 16 + quad * 4 + reg;
        float g = gw[(size_t)r * 4 + kexp];
#pragma unroll
        for (int j = 0; j < 4; j++) {
          int n = rowB0 + wn + j * 16 + fr;
          float v = acc[i][j][reg] + bias[colOff + n];
          Cb[(size_t)r * ldc + n] = f2bf(gelu_fast(v) * g);
        }
      }
    }
  } else {
    float* Cf = (float*)C;
#pragma unroll
    for (int i = 0; i < 4; i++) {
#pragma unroll
      for (int reg = 0; reg < 4; reg++) {
        int r = rowA0 + wm + i * 16 + quad * 4 + reg;
        size_t t4 = (size_t)r * 4;
        float g0 = gw[t4], g1 = gw[t4 + 1], g2 = gw[t4 + 2], g3 = gw[t4 + 3];
#pragma unroll
        for (int j = 0; j < 4; j++) {
          int n = rowB0 + wn + j * 16 + fr;
          size_t ci = (size_t)r * 512 + n;
          float v = acc[i][j][reg];
          if (accum) v += Cf[ci];
          else v += g0 * bias[n] + g1 * bias[512 + n] +
                    g2 * bias[1024 + n] + g3 * bias[1536 + n];
          Cf[ci] = v;
        }
      }
    }
  }
}

#undef LDALL
#undef MMH

// ---------------- launch ----------------

extern "C" void kernel_launch(void* const* d_in, const int* in_sizes, int n_in,
                              void* d_out, int out_size, void* d_ws, size_t ws_size,
                              hipStream_t stream) {
  (void)in_sizes; (void)n_in; (void)out_size;
  const float* x      = (const float*)d_in[0];
  const float* gate_w = (const float*)d_in[1];
  const float* gate_b = (const float*)d_in[2];
  const float* w1     = (const float*)d_in[3];
  const float* b1     = (const float*)d_in[4];
  const float* w2     = (const float*)d_in[5];
  const float* b2     = (const float*)d_in[6];

  char* ws = (char*)d_ws;
  int*            idx   = (int*)(ws + 0);                //  16 B
  float*          gw    = (float*)(ws + 4096);           // 256 KB  [T,4]
  float*          b1cat = (float*)(ws + 266240);         //  32 KB
  float*          b2sel = (float*)(ws + 299008);         //   8 KB
  float*          kpart = (float*)(ws + 307200);         // 256 KB  [128,512]
  unsigned short* xbf   = (unsigned short*)(ws + 831488);      // 16.8 MB [T,512]
  unsigned short* w1t   = (unsigned short*)(ws + 17608704);    //  8.4 MB [8192,512]
  unsigned short* w2t   = (unsigned short*)(ws + 25997312);    //  8.4 MB [512,8192]
  unsigned short* hbuf  = (unsigned short*)(ws + 34385920);    // h' slab
  const size_t HBUF_OFF = 34385920;

  size_t avail = ws_size > HBUF_OFF ? ws_size - HBUF_OFF : 0;
  int nslab = 1;
  while (nslab < 16 && (size_t)16384 * (8192 / nslab) * 2 > avail) nslab <<= 1;
  const int slabDF = 8192 / nslab;

  reduce_part<<<128, 512, 0, stream>>>(x, kpart);
  gate_all<<<1, 1024, 0, stream>>>(kpart, gate_w, gate_b, b1, b2, idx, b1cat, b2sel);
  prep_fused<<<6144, 256, 0, stream>>>(x, gate_w, gate_b, idx, gw, xbf,
                                       w1, w2, w1t, w2t);

  for (int s = 0; s < nslab; s++) {
    const int c0 = s * slabDF;
    // gemm1 (K=512, gelu epilogue): 128^2 2-barrier, 3 blocks/CU.
    gemm_bt<1><<<dim3(128, slabDF / 128), 256, 0, stream>>>(
        xbf, w1t + (size_t)c0 * 512, hbuf,
        /*K=*/512, /*lda=*/512, /*ldb=*/512, /*ldc=*/slabDF,
        gw, b1cat, c0, 0);
    // gemm2 (long K=slabDF): 128^2 4-phase counted-vmcnt, 2 blocks/CU.
    gemm4p<2><<<dim3(128, 4), 256, 0, stream>>>(
        hbuf, w2t + c0, (float*)d_out,
        /*K=*/slabDF, /*lda=*/slabDF, /*ldb=*/8192, /*ldc=*/512,
        gw, b2sel, 0, s > 0);
  }
}

// Round 7
// 499.598 us; speedup vs baseline: 1.0313x; 1.0313x over previous
//
#include <hip/hip_runtime.h>
#include <hip/hip_bf16.h>
#include <cstdint>
#include <cstddef>

typedef __attribute__((ext_vector_type(8))) short short8;
typedef __attribute__((ext_vector_type(4))) float f32x4;

#define AS1U32(p) ((const __attribute__((address_space(1))) uint32_t*)(p))
#define AS3U32(p) ((__attribute__((address_space(3))) uint32_t*)(p))

__device__ __forceinline__ unsigned short f2bf(float v) {
  union { float f; uint32_t u; } a; a.f = v;
  uint32_t u = a.u;
  u += 0x7FFFu + ((u >> 16) & 1u);   // round-to-nearest-even
  return (unsigned short)(u >> 16);
}

// gelu(x) = x * sigmoid(2u), u = sqrt(2/pi)(x + 0.044715 x^3)
// exp2-folded: sig = 1/(1+exp2(x*(A + B*x^2))), A = -2*c0*log2e, B = A*c1
// (round-6 A/B: gemm_bt epilogue VALUBusy 55 -> 50, dur 91 -> 88)
__device__ __forceinline__ float gelu_fast(float x) {
  const float A = -2.302118142f;      // -2*0.7978845608*1.4426950409
  const float B = -0.102943494f;      // A*0.044715
  float x2 = x * x;
  float t = x * __builtin_fmaf(B, x2, A);
  float e = __builtin_amdgcn_exp2f(t);
  return x * __builtin_amdgcn_rcpf(1.0f + e);
}

// ---------------- prologue kernels (round-3 proven config, P ~= 176us) ----------------

// partial token-sums: kpart[b*512+d] = sum_{i<64} x[(b*64+i)*512+d]
// 256 blocks (full machine; round-6's 128-block variant idled half the GPU).
__global__ __launch_bounds__(512)
void reduce_part(const float* __restrict__ x, float* __restrict__ kpart) {
  const int d = threadIdx.x;
  const int b = blockIdx.x;
  float s = 0.f;
#pragma unroll 4
  for (int i = 0; i < 64; i++)
    s += x[((size_t)b * 64 + i) * 512 + d];
  kpart[(size_t)b * 512 + d] = s;
}

__global__ __launch_bounds__(1024)
void gate_all(const float* __restrict__ kpart,
              const float* __restrict__ gate_w,
              const float* __restrict__ gate_b,
              const float* __restrict__ b1, const float* __restrict__ b2,
              int* __restrict__ idxout,
              float* __restrict__ b1cat, float* __restrict__ b2sel) {
  __shared__ float ksum2[2][512];
  __shared__ float coarse[16];
  __shared__ int idxl[4];
  const int t = threadIdx.x;
  {
    const int d = t & 511, h = t >> 9;
    float s = 0.f;
    for (int p = h * 128; p < h * 128 + 128; p++) s += kpart[(size_t)p * 512 + d];
    ksum2[h][d] = s;
  }
  __syncthreads();
  {
    const int wave = t >> 6, lane = t & 63;
    const int d0 = lane * 8;
    float s = 0.f;
#pragma unroll
    for (int j = 0; j < 8; j++)
      s += gate_w[wave * 512 + d0 + j] * (ksum2[0][d0 + j] + ksum2[1][d0 + j]);
#pragma unroll
    for (int off = 32; off >= 1; off >>= 1) s += __shfl_down(s, off, 64);
    if (lane == 0) coarse[wave] = s + gate_b[wave];
  }
  __syncthreads();
  if (t == 0) {
    unsigned taken = 0;
    for (int r = 0; r < 4; r++) {
      float best = -3.4e38f; int bi = 0;
      for (int e = 0; e < 16; e++)
        if (!((taken >> e) & 1u) && coarse[e] > best) { best = coarse[e]; bi = e; }
      taken |= 1u << bi;
      idxl[r] = bi; idxout[r] = bi;
    }
  }
  __syncthreads();
  for (int i = t; i < 8192; i += 1024)
    b1cat[i] = b1[(size_t)idxl[i >> 11] * 2048 + (i & 2047)];
  for (int i = t; i < 2048; i += 1024)
    b2sel[i] = b2[(size_t)idxl[i >> 9] * 512 + (i & 511)];
}

__global__ __launch_bounds__(256)
void transpose_all(const float* __restrict__ w1, const float* __restrict__ w2,
                   unsigned short* __restrict__ w1t, unsigned short* __restrict__ w2t,
                   const int* __restrict__ idx) {
  __shared__ float tl[64][65];
  const int tid = threadIdx.x;
  const int ty = tid >> 6, tx = tid & 63;
  const int z = blockIdx.z;
  const float* src; unsigned short* dbase; int C, dstLd, r0, c0;
  if (z < 4) {
    src = w1 + (size_t)idx[z] * 512 * 2048;
    dbase = w1t + (size_t)z * 2048 * 512;
    C = 2048; dstLd = 512;
    r0 = blockIdx.x * 64; c0 = blockIdx.y * 64;
  } else {
    src = w2 + (size_t)idx[z - 4] * 2048 * 512;
    dbase = w2t + (size_t)(z - 4) * 2048;
    C = 512; dstLd = 8192;
    r0 = blockIdx.y * 64; c0 = blockIdx.x * 64;
  }
#pragma unroll
  for (int i = 0; i < 16; i++) {
    int r = ty * 16 + i;
    tl[r][tx] = src[(size_t)(r0 + r) * C + c0 + tx];
  }
  __syncthreads();
#pragma unroll
  for (int i = 0; i < 16; i++) {
    int rr = ty * 16 + i;
    dbase[(size_t)(c0 + rr) * dstLd + r0 + tx] = f2bf(tl[tx][rr]);
  }
}

__global__ __launch_bounds__(256)
void gate_softmax_xconv(const float* __restrict__ x,
                        const float* __restrict__ gate_w,
                        const float* __restrict__ gate_b,
                        const int* __restrict__ idx,
                        float* __restrict__ gwout,
                        unsigned short* __restrict__ xbf) {
  __shared__ float wsel[4][512];
  __shared__ float bsel[4];
  const int tid = threadIdx.x;
  for (int i = tid; i < 2048; i += 256) {
    int k = i >> 9;
    wsel[k][i & 511] = gate_w[(size_t)idx[k] * 512 + (i & 511)];
  }
  if (tid < 4) bsel[tid] = gate_b[idx[tid]];
  __syncthreads();
  const int wave = tid >> 6, lane = tid & 63;
  const int t = blockIdx.x * 4 + wave;
  const float* xr = x + (size_t)t * 512 + lane * 8;
  float4 v0 = ((const float4*)xr)[0];
  float4 v1 = ((const float4*)xr)[1];
  float vals[8] = {v0.x, v0.y, v0.z, v0.w, v1.x, v1.y, v1.z, v1.w};
  short8 pk;
#pragma unroll
  for (int j = 0; j < 8; j++) pk[j] = (short)f2bf(vals[j]);
  *(short8*)(xbf + (size_t)t * 512 + lane * 8) = pk;
  float a0 = 0.f, a1 = 0.f, a2 = 0.f, a3 = 0.f;
  const int dbase = lane * 8;
#pragma unroll
  for (int j = 0; j < 8; j++) {
    float xv = vals[j];
    a0 += xv * wsel[0][dbase + j];
    a1 += xv * wsel[1][dbase + j];
    a2 += xv * wsel[2][dbase + j];
    a3 += xv * wsel[3][dbase + j];
  }
#pragma unroll
  for (int off = 32; off >= 1; off >>= 1) {
    a0 += __shfl_down(a0, off, 64);
    a1 += __shfl_down(a1, off, 64);
    a2 += __shfl_down(a2, off, 64);
    a3 += __shfl_down(a3, off, 64);
  }
  if (lane == 0) {
    float l0 = a0 + bsel[0], l1 = a1 + bsel[1], l2 = a2 + bsel[2], l3 = a3 + bsel[3];
    float m = fmaxf(fmaxf(l0, l1), fmaxf(l2, l3));
    float e0 = __expf(l0 - m), e1 = __expf(l1 - m);
    float e2 = __expf(l2 - m), e3 = __expf(l3 - m);
    float inv = 1.0f / (e0 + e1 + e2 + e3);
    float* o = gwout + (size_t)t * 4;
    o[0] = e0 * inv; o[1] = e1 * inv; o[2] = e2 * inv; o[3] = e3 * inv;
  }
}

// ---------------- gemm_bt: 128x128 2-barrier kernel (gemm1) ----------------
// K=512 short-K, gelu epilogue: 32 KiB LDS -> 3 blocks/CU (measured 37% occ);
// cross-block overlap hides barrier drains + epilogue. Measured 87.4-88.7 us
// with exp2 gelu (round 6). Pipelined variants all slower (rounds 1/4/5).
template <int EPI>
__global__ __launch_bounds__(256, 2)
void gemm_bt(const unsigned short* __restrict__ A,
             const unsigned short* __restrict__ Bt,
             void* __restrict__ C, int K, int lda, int ldb, int ldc,
             const float* __restrict__ gw,
             const float* __restrict__ bias, int colOff, int accum) {
  __shared__ unsigned short lA[128 * 64];
  __shared__ unsigned short lB[128 * 64];
  const int tid = threadIdx.x;
  const int wave = tid >> 6;
  const int lane = tid & 63;
  const int rowA0 = blockIdx.x * 128;
  const int rowB0 = blockIdx.y * 128;

  f32x4 acc[4][4];
#pragma unroll
  for (int i = 0; i < 4; i++)
#pragma unroll
    for (int j = 0; j < 4; j++) acc[i][j] = (f32x4){0.f, 0.f, 0.f, 0.f};

  const int lrow = lane >> 3;
  const int lslot = lane & 7;
  const int gchunk = lslot ^ lrow;
  const int fr = lane & 15;
  const int quad = lane >> 4;
  const int wm = (wave >> 1) * 64;
  const int wn = (wave & 1) * 64;
  const int swz = fr & 7;

  for (int kt = 0; kt < K; kt += 64) {
#pragma unroll
    for (int c = 0; c < 4; c++) {
      int r = wave * 32 + c * 8 + lrow;
      const unsigned short* gp = A + (size_t)(rowA0 + r) * lda + kt + gchunk * 8;
      __builtin_amdgcn_global_load_lds(AS1U32(gp), AS3U32(lA + (wave * 32 + c * 8) * 64), 16, 0, 0);
    }
#pragma unroll
    for (int c = 0; c < 4; c++) {
      int r = wave * 32 + c * 8 + lrow;
      const unsigned short* gp = Bt + (size_t)(rowB0 + r) * ldb + kt + gchunk * 8;
      __builtin_amdgcn_global_load_lds(AS1U32(gp), AS3U32(lB + (wave * 32 + c * 8) * 64), 16, 0, 0);
    }
    __syncthreads();
#pragma unroll
    for (int ks = 0; ks < 2; ks++) {
      short8 af[4], bfr[4];
      const int c = ks * 4 + quad;
      const int slot = (c ^ swz) << 3;
#pragma unroll
      for (int i = 0; i < 4; i++)
        af[i] = *(const short8*)(lA + (wm + i * 16 + fr) * 64 + slot);
#pragma unroll
      for (int j = 0; j < 4; j++)
        bfr[j] = *(const short8*)(lB + (wn + j * 16 + fr) * 64 + slot);
#pragma unroll
      for (int i = 0; i < 4; i++)
#pragma unroll
        for (int j = 0; j < 4; j++)
          acc[i][j] = __builtin_amdgcn_mfma_f32_16x16x32_bf16(af[i], bfr[j], acc[i][j], 0, 0, 0);
    }
    __syncthreads();
  }

  if (EPI == 1) {
    unsigned short* Cb = (unsigned short*)C;
    const int kexp = (colOff + rowB0) >> 11;
#pragma unroll
    for (int i = 0; i < 4; i++) {
#pragma unroll
      for (int reg = 0; reg < 4; reg++) {
        int r = rowA0 + wm + i * 16 + quad * 4 + reg;
        float g = gw[(size_t)r * 4 + kexp];
#pragma unroll
        for (int j = 0; j < 4; j++) {
          int n = rowB0 + wn + j * 16 + fr;
          float v = acc[i][j][reg] + bias[colOff + n];
          Cb[(size_t)r * ldc + n] = f2bf(gelu_fast(v) * g);
        }
      }
    }
  } else {
    float* Cf = (float*)C;
#pragma unroll
    for (int i = 0; i < 4; i++) {
#pragma unroll
      for (int reg = 0; reg < 4; reg++) {
        int r = rowA0 + wm + i * 16 + quad * 4 + reg;
        size_t t4 = (size_t)r * 4;
        float g0 = gw[t4], g1 = gw[t4 + 1], g2 = gw[t4 + 2], g3 = gw[t4 + 3];
#pragma unroll
        for (int j = 0; j < 4; j++) {
          int n = rowB0 + wn + j * 16 + fr;
          size_t ci = (size_t)r * 512 + n;
          float v = acc[i][j][reg];
          if (accum) v += Cf[ci];
          else v += g0 * bias[n] + g1 * bias[512 + n] +
                    g2 * bias[1024 + n] + g3 * bias[1536 + n];
          Cf[ci] = v;
        }
      }
    }
  }
}

// ---------------- gemm4p: 4-phase double-buffered 128x128 tile (gemm2) ----------------
// Long-K (slabDF) only. 64 KiB LDS -> 2 blocks/CU; counted-vmcnt pipeline +
// cross-block overlap. Measured ~62 us/slab (rounds 5/6 delta arithmetic).
//   P0: ds_read ALL buf0 frags | BAR | lgkm0 | MFMA ks=0 | BAR
//   P1: stage next buf0 tile (8 loads) | MFMA ks=1 | vmcnt(8) | BAR
//   P2/P3: same for buf1. VMW(8) = oldest in-flight tile landed.
// No XCD swizzle: natural lin id stride for A-sharing blocks is gridDim.x
// = 0 mod 8 -> they share one XCD L2 (round-2 lesson).

#define CFENCE asm volatile("" ::: "memory")
#define BAR    do { CFENCE; __builtin_amdgcn_s_barrier(); CFENCE; } while (0)
#define LGKM0  do { asm volatile("s_waitcnt lgkmcnt(0)" ::: "memory"); \
                    __builtin_amdgcn_sched_barrier(0); } while (0)
#define SCHEDB __builtin_amdgcn_sched_barrier(0)
#define VMW(n) asm volatile("s_waitcnt vmcnt(" #n ")" ::: "memory")

#define LDALL(abuf, bbuf)                                                   \
  do {                                                                      \
    _Pragma("unroll")                                                       \
    for (int i_ = 0; i_ < 4; i_++)                                          \
      _Pragma("unroll")                                                     \
      for (int ks_ = 0; ks_ < 2; ks_++)                                     \
        aF[i_][ks_] = *(const short8*)((abuf) +                             \
            (size_t)(wm + i_ * 16 + fr) * 64 +                              \
            (((ks_ * 4 + quad) ^ swz) << 3));                               \
    _Pragma("unroll")                                                       \
    for (int j_ = 0; j_ < 4; j_++)                                          \
      _Pragma("unroll")                                                     \
      for (int ks_ = 0; ks_ < 2; ks_++)                                     \
        bF[j_][ks_] = *(const short8*)((bbuf) +                             \
            (size_t)(wn + j_ * 16 + fr) * 64 +                              \
            (((ks_ * 4 + quad) ^ swz) << 3));                               \
  } while (0)

#define MMH(ks)                                                             \
  do {                                                                      \
    __builtin_amdgcn_s_setprio(1);                                          \
    _Pragma("unroll")                                                       \
    for (int i_ = 0; i_ < 4; i_++)                                          \
      _Pragma("unroll")                                                     \
      for (int j_ = 0; j_ < 4; j_++)                                        \
        acc[i_][j_] = __builtin_amdgcn_mfma_f32_16x16x32_bf16(              \
            aF[i_][ks], bF[j_][ks], acc[i_][j_], 0, 0, 0);                  \
    __builtin_amdgcn_s_setprio(0);                                          \
  } while (0)

template <int EPI>
__global__ __launch_bounds__(256, 2)
void gemm4p(const unsigned short* __restrict__ A,
            const unsigned short* __restrict__ Bt,
            void* __restrict__ C, int K, int lda, int ldb, int ldc,
            const float* __restrict__ gw,
            const float* __restrict__ bias, int colOff, int accum) {
  __shared__ unsigned short lds[4 * 128 * 64];
  const int tid = threadIdx.x;
  const int wave = tid >> 6, lane = tid & 63;
  const int lrow = lane >> 3, lslot = lane & 7, gch = lslot ^ lrow;
  const int fr = lane & 15, quad = lane >> 4, swz = fr & 7;
  const int wm = (wave >> 1) * 64, wn = (wave & 1) * 64;
  const int rowA0 = blockIdx.x * 128;
  const int rowB0 = blockIdx.y * 128;

  unsigned short* const A0 = lds;
  unsigned short* const B0 = lds + 128 * 64;
  unsigned short* const A1 = lds + 2 * 128 * 64;
  unsigned short* const B1 = lds + 3 * 128 * 64;

  auto stT = [&](unsigned short* ab, unsigned short* bb, int kt) {
#pragma unroll
    for (int c = 0; c < 4; c++) {
      int r = wave * 32 + c * 8 + lrow;
      const unsigned short* gp = A + (size_t)(rowA0 + r) * lda + kt + gch * 8;
      __builtin_amdgcn_global_load_lds(AS1U32(gp), AS3U32(ab + (wave * 32 + c * 8) * 64), 16, 0, 0);
    }
#pragma unroll
    for (int c = 0; c < 4; c++) {
      int r = wave * 32 + c * 8 + lrow;
      const unsigned short* gp = Bt + (size_t)(rowB0 + r) * ldb + kt + gch * 8;
      __builtin_amdgcn_global_load_lds(AS1U32(gp), AS3U32(bb + (wave * 32 + c * 8) * 64), 16, 0, 0);
    }
  };

  f32x4 acc[4][4];
#pragma unroll
  for (int i = 0; i < 4; i++)
#pragma unroll
    for (int j = 0; j < 4; j++) acc[i][j] = (f32x4){0.f, 0.f, 0.f, 0.f};

  short8 aF[4][2];
  short8 bF[4][2];

  // ---- prologue: tile0 -> buf0, tile1 -> buf1 ----
  stT(A0, B0, 0);
  stT(A1, B1, 64);
  VMW(8);            // oldest 8 = tile0 landed (tile1 may be in flight)
  BAR;

  const int niter = K >> 7;   // two 64-K tiles per iteration
  for (int i = 0; i < niter - 1; i++) {
    const int kt = i * 128;
    LDALL(A0, B0);
    BAR; LGKM0; MMH(0); BAR;
    stT(A0, B0, kt + 128); SCHEDB;
    MMH(1); VMW(8); BAR;
    LDALL(A1, B1);
    BAR; LGKM0; MMH(0); BAR;
    stT(A1, B1, kt + 192); SCHEDB;
    MMH(1); VMW(8); BAR;
  }
  // ---- peeled last iteration (no staging) ----
  LDALL(A0, B0);
  BAR; LGKM0; MMH(0); BAR;
  MMH(1); VMW(0); BAR;
  LDALL(A1, B1);
  BAR; LGKM0; MMH(0); BAR;
  MMH(1);

  // ---- epilogue ----
  if (EPI == 1) {
    unsigned short* Cb = (unsigned short*)C;
    const int kexp = (colOff + rowB0) >> 11;
#pragma unroll
    for (int i = 0; i < 4; i++) {
#pragma unroll
      for (int reg = 0; reg < 4; reg++) {
        int r = rowA0 + wm + i * 16 + quad * 4 + reg;
        float g = gw[(size_t)r * 4 + kexp];
#pragma unroll
        for (int j = 0; j < 4; j++) {
          int n = rowB0 + wn + j * 16 + fr;
          float v = acc[i][j][reg] + bias[colOff + n];
          Cb[(size_t)r * ldc + n] = f2bf(gelu_fast(v) * g);
        }
      }
    }
  } else {
    float* Cf = (float*)C;
#pragma unroll
    for (int i = 0; i < 4; i++) {
#pragma unroll
      for (int reg = 0; reg < 4; reg++) {
        int r = rowA0 + wm + i * 16 + quad * 4 + reg;
        size_t t4 = (size_t)r * 4;
        float g0 = gw[t4], g1 = gw[t4 + 1], g2 = gw[t4 + 2], g3 = gw[t4 + 3];
#pragma unroll
        for (int j = 0; j < 4; j++) {
          int n = rowB0 + wn + j * 16 + fr;
          size_t ci = (size_t)r * 512 + n;
          float v = acc[i][j][reg];
          if (accum) v += Cf[ci];
          else v += g0 * bias[n] + g1 * bias[512 + n] +
                    g2 * bias[1024 + n] + g3 * bias[1536 + n];
          Cf[ci] = v;
        }
      }
    }
  }
}

#undef LDALL
#undef MMH

// ---------------- launch ----------------

extern "C" void kernel_launch(void* const* d_in, const int* in_sizes, int n_in,
                              void* d_out, int out_size, void* d_ws, size_t ws_size,
                              hipStream_t stream) {
  (void)in_sizes; (void)n_in; (void)out_size;
  const float* x      = (const float*)d_in[0];
  const float* gate_w = (const float*)d_in[1];
  const float* gate_b = (const float*)d_in[2];
  const float* w1     = (const float*)d_in[3];
  const float* b1     = (const float*)d_in[4];
  const float* w2     = (const float*)d_in[5];
  const float* b2     = (const float*)d_in[6];

  char* ws = (char*)d_ws;
  int*            idx   = (int*)(ws + 0);                //  16 B
  float*          gw    = (float*)(ws + 4096);           // 256 KB  [T,4]
  float*          b1cat = (float*)(ws + 266240);         //  32 KB
  float*          b2sel = (float*)(ws + 299008);         //   8 KB
  float*          kpart = (float*)(ws + 307200);         // 512 KB  [256,512]
  unsigned short* xbf   = (unsigned short*)(ws + 831488);      // 16.8 MB [T,512]
  unsigned short* w1t   = (unsigned short*)(ws + 17608704);    //  8.4 MB [8192,512]
  unsigned short* w2t   = (unsigned short*)(ws + 25997312);    //  8.4 MB [512,8192]
  unsigned short* hbuf  = (unsigned short*)(ws + 34385920);    // h' slab
  const size_t HBUF_OFF = 34385920;

  size_t avail = ws_size > HBUF_OFF ? ws_size - HBUF_OFF : 0;
  int nslab = 1;
  while (nslab < 16 && (size_t)16384 * (8192 / nslab) * 2 > avail) nslab <<= 1;
  const int slabDF = 8192 / nslab;

  reduce_part<<<256, 512, 0, stream>>>(x, kpart);
  gate_all<<<1, 1024, 0, stream>>>(kpart, gate_w, gate_b, b1, b2, idx, b1cat, b2sel);
  transpose_all<<<dim3(8, 32, 8), 256, 0, stream>>>(w1, w2, w1t, w2t, idx);
  gate_softmax_xconv<<<4096, 256, 0, stream>>>(x, gate_w, gate_b, idx, gw, xbf);

  for (int s = 0; s < nslab; s++) {
    const int c0 = s * slabDF;
    // gemm1 (K=512, gelu epilogue): 128^2 2-barrier, 3 blocks/CU. ~88 us.
    gemm_bt<1><<<dim3(128, slabDF / 128), 256, 0, stream>>>(
        xbf, w1t + (size_t)c0 * 512, hbuf,
        /*K=*/512, /*lda=*/512, /*ldb=*/512, /*ldc=*/slabDF,
        gw, b1cat, c0, 0);
    // gemm2 (long K=slabDF): 128^2 4-phase counted-vmcnt, 2 blocks/CU. ~62 us.
    gemm4p<2><<<dim3(128, 4), 256, 0, stream>>>(
        hbuf, w2t + c0, (float*)d_out,
        /*K=*/slabDF, /*lda=*/slabDF, /*ldb=*/8192, /*ldc=*/512,
        gw, b2sel, 0, s > 0);
  }
}